// Round 11
// baseline (218.024 us; speedup 1.0000x reference)
//
#include <hip/hip_runtime.h>
#include <math.h>

#define NQ  12
#define TPB 512

typedef __attribute__((ext_vector_type(2))) float f2;

// ================= compile-time GF(2) machinery (r8/r9-validated core) =================
// Folded space: gate on qubit q layer l pairs x <-> x^v, role=parity(r&x), r_j.v_i=delta_ij.
// RADIX-8 / TPB=512: 16 passes x 3 gates (pass p: layer p/4, qubits 3*(p%4)+j).
// Thread t (9 bits: lane 6 + wave 3) slot z (3 bits): x = B.t ^ W.w ^ C[z].
// PAIRED passes (2m,2m+1): shared lane basis B[0..5] in 9-dim S, shared wave basis
// W[0..2] outside S -> intra-pair transition is wave-internal ds_bpermute.
// Boundary: elem E = e ^ (((e>>4)&3)<<1), e = z | t<<3. Writer stores SLOT-pair data
// at SWIZZLED position (r10 bug: indexed both by zz -> identity layout; fixed).

struct GF12 { unsigned row[12]; };

constexpr GF12 gf_id(){ GF12 m{}; for(int i=0;i<12;i++) m.row[i]=1u<<i; return m; }
constexpr GF12 gf_mul(const GF12&A,const GF12&B){
  GF12 r{};
  for(int i=0;i<12;i++){ unsigned acc=0;
    for(int k=0;k<12;k++) if((A.row[i]>>k)&1u) acc ^= B.row[k];
    r.row[i]=acc; }
  return r;
}
constexpr unsigned gf_apply(const GF12&A, unsigned x){
  unsigned y=0;
  for(int i=0;i<12;i++) y |= (unsigned)(__builtin_popcount(A.row[i]&x)&1)<<i;
  return y;
}
constexpr GF12 gf_cnot(int q){ GF12 m=gf_id(); int c=11-q, t=11-((q+1)%12); m.row[t]^=(1u<<c); return m; }
constexpr GF12 gf_inv(const GF12&A){
  unsigned a[12], inv[12];
  for(int i=0;i<12;i++){ a[i]=A.row[i]; inv[i]=1u<<i; }
  for(int c=0;c<12;c++){
    int p=-1;
    for(int r2=c;r2<12;r2++) if((a[r2]>>c)&1u){p=r2;break;}
    if(p<0) continue;
    unsigned ta=a[c]; a[c]=a[p]; a[p]=ta;
    unsigned ti=inv[c]; inv[c]=inv[p]; inv[p]=ti;
    for(int r2=0;r2<12;r2++) if(r2!=c && ((a[r2]>>c)&1u)){ a[r2]^=a[c]; inv[r2]^=inv[c]; }
  }
  GF12 R{}; for(int i=0;i<12;i++) R.row[i]=inv[i];
  return R;
}

struct Red { unsigned arr[12]; int hb[12]; int n; };
constexpr unsigned red_reduce(const Red& R, unsigned y){
  for(int i=0;i<R.n;i++) if((y>>R.hb[i])&1u) y ^= R.arr[i];
  return y;
}
constexpr bool red_add(Red& R, unsigned cand){
  unsigned y = red_reduce(R, cand);
  if(!y) return false;
  int h=0;
  for(int b2=11;b2>=1;b2--) if((y>>b2)&1u){ h=b2; break; }
  R.arr[R.n]=y; R.hb[R.n]=h; R.n++;
  return true;
}

struct PairT {
  unsigned M0[3], M1[3];   // role masks (9-bit over t)
  unsigned sz[8], gx[8];   // bpermute: src slot, lane-xor per dest slot
  unsigned rB[9], roff[8]; // read basis/offsets in prev-boundary E space (m>0)
};
struct AllT { PairT pr[8]; unsigned mq[12], uq[12]; bool ok; };

constexpr AllT makeAll(){
  AllT T{}; T.ok=true;
  GF12 D=gf_id(); for(int q=0;q<12;q++) D=gf_mul(gf_cnot(q),D);
  GF12 Cm=gf_id(); for(int q=11;q>=0;q--) Cm=gf_mul(gf_cnot(q),Cm);
  unsigned V[16][3]{}, R[16][3]{}, rfin[12]{};
  GF12 Mm=gf_id(), Mi=gf_id();
  for(int l=0;l<4;l++){
    for(int q=0;q<12;q++){
      int b=11-q; unsigned v=0;
      for(int j=0;j<12;j++) v|=((Mi.row[j]>>b)&1u)<<j;
      V[4*l+q/3][q%3]=v; R[4*l+q/3][q%3]=Mm.row[b];
    }
    Mm=gf_mul(D,Mm); Mi=gf_mul(Cm,Mi);
  }
  for(int q=0;q<12;q++) rfin[q]=Mm.row[11-q];

  // boundary swizzle: E = e ^ (((e>>4)&3)<<1); e = z(0..2) | lane(3..8) | wave(9..11)
  GF12 Sg=gf_id(); Sg.row[1]|=1u<<4; Sg.row[2]|=1u<<5;

  GF12 Tprev{}, Tprev_inv{};
  for(int m=0;m<8;m++){
    const int p0=2*m, p1=p0+1;
    for(int pp=p0;pp<=p1;pp++) for(int j=0;j<3;j++) for(int i=0;i<3;i++){
      int par=__builtin_popcount(R[pp][j]&V[pp][i])&1;
      if(par!=((i==j)?1:0)) T.ok=false;
    }
    // S: 9-dim containing span{V0 u V1}
    Red S{};
    for(int i=0;i<3;i++){ red_add(S,V[p0][i]); red_add(S,V[p1][i]); }
    if(S.n!=6) T.ok=false;
    for(unsigned x=1;x<4096 && S.n<9;x++) red_add(S,x);
    if(S.n!=9) T.ok=false;
    // shared wave vectors outside S
    unsigned W[3]{};
    { Red SB=S;
      for(int k=0;k<3;k++){
        unsigned pick=0;
        for(unsigned x=1;x<4096 && !pick;x++) if(red_reduce(SB,x)) pick=x;
        if(!pick) T.ok=false; else red_add(SB,pick);
        W[k]=pick;
      }
      if(SB.n!=12) T.ok=false;
    }
    Red RA{}, RB{};
    for(int i=0;i<3;i++){ red_add(RA,V[p0][i]); red_add(RB,V[p1][i]); }
    unsigned B[6]{};
    Red resR{};
    for(int k=0;k<6;k++){
      unsigned pick=0;
      if(m>0){
        unsigned res=(k<4)?(1u<<k):0u;
        for(unsigned hi=(k<4)?0u:1u; hi<256 && !pick; hi++){
          unsigned y=res|(hi<<4);
          unsigned x=gf_apply(Tprev_inv,y);
          if(red_reduce(S,x)) continue;      // must lie in S
          if(!red_reduce(RA,x)) continue;
          if(!red_reduce(RB,x)) continue;
          pick=x;
        }
        for(unsigned y=1;y<4096 && !pick;y++){
          unsigned x=gf_apply(Tprev_inv,y);
          if(red_reduce(S,x)) continue;
          if(!red_reduce(RA,x)) continue;
          if(!red_reduce(RB,x)) continue;
          if(k<4){ unsigned rb=y&15u; if(!rb || !red_reduce(resR,rb)) continue; }
          pick=x;
        }
      }
      if(!pick){
        for(unsigned x=1;x<4096 && !pick;x++){
          if(red_reduce(S,x)) continue;
          if(!red_reduce(RA,x)) continue;
          if(!red_reduce(RB,x)) continue;
          pick=x;
        }
      }
      if(!pick){ T.ok=false; pick=1; }
      if(m>0 && k<4){ unsigned rb=gf_apply(Tprev,pick)&15u; if(rb) red_add(resR,rb); }
      red_add(RA,pick); red_add(RB,pick);
      B[k]=pick;
    }
    if(RA.n!=9 || RB.n!=9) T.ok=false;
    // frame Z for p1: coords (z,lane,wave) -> x ; Tp = x -> coords
    GF12 Z{};
    for(int i=0;i<12;i++){
      unsigned rr=0;
      for(int k=0;k<3;k++) rr |= ((V[p1][k]>>i)&1u)<<k;
      for(int k=0;k<6;k++) rr |= ((B[k]>>i)&1u)<<(3+k);
      for(int k=0;k<3;k++) rr |= ((W[k]>>i)&1u)<<(9+k);
      Z.row[i]=rr;
    }
    GF12 Tp=gf_inv(Z);
    { GF12 I2=gf_mul(Tp,Z); for(int i=0;i<12;i++) if(I2.row[i]!=(1u<<i)) T.ok=false; }
    // role masks (9-bit over t: lane bits 0..5 from B, wave bits 6..8 from W)
    for(int j=0;j<3;j++){
      unsigned m0=0,m1=0;
      for(int k=0;k<6;k++){
        m0 |= (unsigned)(__builtin_popcount(R[p0][j]&B[k])&1)<<k;
        m1 |= (unsigned)(__builtin_popcount(R[p1][j]&B[k])&1)<<k;
      }
      for(int k=0;k<3;k++){
        m0 |= (unsigned)(__builtin_popcount(R[p0][j]&W[k])&1)<<(6+k);
        m1 |= (unsigned)(__builtin_popcount(R[p1][j]&W[k])&1)<<(6+k);
      }
      T.pr[m].M0[j]=m0; T.pr[m].M1[j]=m1;
    }
    // bpermute decomposition: V[p0][i] over [V[p1]|B|W]; wave part must vanish
    unsigned zeta[3]{}, gam[3]{};
    for(int i=0;i<3;i++){
      unsigned d=gf_apply(Tp,V[p0][i]);
      if(d>>9) T.ok=false;
      zeta[i]=d&7u; gam[i]=(d>>3)&63u;
    }
    unsigned zmap[8]{}; bool seen[8]{};
    for(int z=0;z<8;z++){
      unsigned zz=0;
      for(int i=0;i<3;i++) if((z>>i)&1) zz^=zeta[i];
      zmap[z]=zz;
      if(seen[zz]) T.ok=false; seen[zz]=true;
    }
    for(int zp=0;zp<8;zp++){
      unsigned src=0;
      for(int z=0;z<8;z++) if(zmap[z]==(unsigned)zp) src=(unsigned)z;
      unsigned gg=0;
      for(int i=0;i<3;i++) if((src>>i)&1) gg^=gam[i];
      T.pr[m].sz[zp]=src; T.pr[m].gx[zp]=gg;
    }
    // pair invariant: C0[z] == C1[zmap[z]] ^ B*gamma(z)
    for(int z=0;z<8;z++){
      unsigned c0=0,c1=0,gg=0,bb=0;
      for(int i=0;i<3;i++){
        if((z>>i)&1){ c0^=V[p0][i]; gg^=gam[i]; }
        if((zmap[z]>>i)&1) c1^=V[p1][i];
      }
      for(int k=0;k<6;k++) if((gg>>k)&1) bb^=B[k];
      if((c0^c1^bb)!=0) T.ok=false;
    }
    // read tables (from previous boundary), m>0
    if(m>0){
      for(int k=0;k<6;k++) T.pr[m].rB[k]=gf_apply(Tprev,B[k]);
      for(int k=0;k<3;k++) T.pr[m].rB[6+k]=gf_apply(Tprev,W[k]);
      for(int z=0;z<8;z++){
        unsigned c=0;
        for(int i=0;i<3;i++) if((z>>i)&1) c^=V[p0][i];
        T.pr[m].roff[z]=gf_apply(Tprev,c);
      }
    }
    // next boundary map
    GF12 Tnew=gf_mul(Sg,Tp), Tnew_inv=gf_mul(Z,Sg);
    { GF12 I2=gf_mul(Tnew,Tnew_inv); for(int i=0;i<12;i++) if(I2.row[i]!=(1u<<i)) T.ok=false; }
    Tprev=Tnew; Tprev_inv=Tnew_inv;
    if(m==7){
      for(int q=0;q<12;q++){
        unsigned u=0,mm=0;
        for(int i=0;i<3;i++) u |= (unsigned)(__builtin_popcount(rfin[q]&V[15][i])&1)<<i;
        for(int k=0;k<6;k++) mm |= (unsigned)(__builtin_popcount(rfin[q]&B[k])&1)<<k;
        for(int k=0;k<3;k++) mm |= (unsigned)(__builtin_popcount(rfin[q]&W[k])&1)<<(6+k);
        T.uq[q]=u; T.mq[q]=mm;
      }
    }
  }
  return T;
}

constexpr AllT hA = makeAll();
static_assert(hA.ok, "GF(2) radix-8 paired table self-check failed");

// ---- packed butterfly (r9-validated): 8 v_pk_fma_f32-class ops per pair ----
#define GATE_PK8(SS,PP,JJ,MM) do { \
    constexpr int g_ = 12*((PP)/4) + 3*((PP)%4) + (JJ); \
    constexpr int db_ = 4*g_; \
    constexpr int rg_ = db_>>6; \
    constexpr int di_ = db_&63; \
    const unsigned cur = (rg_==0)?c0:((rg_==1)?c1:c2); \
    const unsigned _sg = ((unsigned)(__popc((MM) & t) & 1)) << 31; \
    const float _ar = __uint_as_float((unsigned)__builtin_amdgcn_readlane((int)cur, di_+0)); \
    const float _ai = __uint_as_float(((unsigned)__builtin_amdgcn_readlane((int)cur, di_+1)) ^ _sg); \
    const float _br = __uint_as_float(((unsigned)__builtin_amdgcn_readlane((int)cur, di_+2)) ^ _sg); \
    const float _bi = __uint_as_float((unsigned)__builtin_amdgcn_readlane((int)cur, di_+3)); \
    const f2 A0 = {_ar,_ar}, A1 = {-_ai,_ai}, B0 = {_br,_br}, B1 = {-_bi,_bi}; \
    _Pragma("unroll") \
    for (int s0=0; s0<8; ++s0){ \
      if ((s0 >> (JJ)) & 1) continue; \
      const int s1 = s0 | (1<<(JJ)); \
      const f2 X = SS[s0], Y = SS[s1]; \
      const f2 Xs = __builtin_shufflevector(X,X,1,0); \
      const f2 Ys = __builtin_shufflevector(Y,Y,1,0); \
      SS[s0] = __builtin_elementwise_fma(A0,X, \
               __builtin_elementwise_fma(A1,Xs, \
               __builtin_elementwise_fma(B0,Y, B1*Ys))); \
      SS[s1] = __builtin_elementwise_fma(A0,Y, \
               __builtin_elementwise_fma(-A1,Ys, \
               __builtin_elementwise_fma(-B0,X, B1*Xs))); \
    } \
  } while(0)

template<int M>
__device__ __forceinline__ void do_pair(f2 S[8], f2 Sn[8],
                                        unsigned c0, unsigned c1, unsigned c2,
                                        unsigned t, float2* s2, float4* s4)
{
  constexpr PairT P = hA.pr[M];
  if constexpr (M > 0){
    unsigned base=0;
    #pragma unroll
    for(int k=0;k<9;++k) base ^= ((t>>k)&1u) ? P.rB[k] : 0u;
    #pragma unroll
    for(int z=0;z<8;++z){ float2 v=s2[base ^ P.roff[z]]; S[z].x=v.x; S[z].y=v.y; }
  }
  // pass p0 = 2M
  GATE_PK8(S,2*M,0,P.M0[0]); GATE_PK8(S,2*M,1,P.M0[1]); GATE_PK8(S,2*M,2,P.M0[2]);
  // wave-internal transition (r8-validated): dest zp pulls src slot sz from lane (t^gx)&63
  #pragma unroll
  for(int zp=0; zp<8; ++zp){
    const int idx=(int)((((t)&63u) ^ P.gx[zp])<<2);
    Sn[zp].x=__uint_as_float((unsigned)__builtin_amdgcn_ds_bpermute(idx,(int)__float_as_uint(S[P.sz[zp]].x)));
    Sn[zp].y=__uint_as_float((unsigned)__builtin_amdgcn_ds_bpermute(idx,(int)__float_as_uint(S[P.sz[zp]].y)));
  }
  // pass p1 = 2M+1
  GATE_PK8(Sn,2*M+1,0,P.M1[0]); GATE_PK8(Sn,2*M+1,1,P.M1[1]); GATE_PK8(Sn,2*M+1,2,P.M1[2]);
  if constexpr (M < 7){
    __syncthreads();                   // all waves' pair-M reads complete
    // element E = (t<<3 | z) ^ (sw in z bits 1..2): SLOT data at SWIZZLED position
    const unsigned sw = ((t>>1)&3u)<<1;
    #pragma unroll
    for(int k=0;k<4;++k){
      const unsigned z0 = 2u*(unsigned)k;                  // slot pair base
      s4[(t<<2) | ((z0 ^ sw)>>1)] =
        make_float4(Sn[z0].x, Sn[z0].y, Sn[z0|1u].x, Sn[z0|1u].y);   // b128 burst
    }
    __syncthreads();                   // writes visible to pair M+1 reads
  }
}

__global__ void __launch_bounds__(TPB, 8)
qgen(const float* __restrict__ noise,
     const float* __restrict__ W1, const float* __restrict__ b1,
     const float* __restrict__ W2, const float* __restrict__ b2,
     const float* __restrict__ W3, const float* __restrict__ b3,
     const float* __restrict__ W4, const float* __restrict__ b4,
     float* __restrict__ out)
{
  __shared__ float2 s2[4096];          // 32 KiB -> 4 blocks/CU x 8 waves = 32 waves/CU
  float*  sf=(float*)s2;
  float4* s4=(float4*)s2;

  const unsigned t = threadIdx.x;      // 0..511
  const int b = blockIdx.x;
  const int lane = t & 63;

  // ---- prologue MLP (r3/r6-validated; scratch aliased into state) ----
  if (t < 12) sf[400+t] = noise[b*12+t];
  __syncthreads();
  if (t < 64){
    float a = b1[t];
    #pragma unroll
    for (int k=0;k<12;++k) a = fmaf(sf[400+k], W1[k*64+t], a);
    sf[192+t] = tanhf(a);
  }
  __syncthreads();
  if (t < 144){
    float a = b2[t];
    #pragma unroll 16
    for (int j=0;j<64;++j) a = fmaf(sf[192+j], W2[j*144+t], a);
    sf[256+t] = a;
  }
  __syncthreads();
  if (t < 48){
    float aa = sf[256+3*t+0]*0.5f, bb = sf[256+3*t+1]*0.5f, c = sf[256+3*t+2]*0.5f;
    float sa,ca,sb,cb,sc2,cc;
    __sincosf(aa,&sa,&ca); __sincosf(bb,&sb,&cb); __sincosf(c,&sc2,&cc);
    float A=cb*ca, B=sb*sa, Cc=sb*ca, Dd=cb*sa;
    s4[t] = make_float4(fmaf(cc,A,  sc2*B),  fmaf(cc,B, -sc2*A),
                        fmaf(-cc,Cc,-sc2*Dd), fmaf(sc2,Cc,-cc*Dd));
  }
  __syncthreads();
  const unsigned* su=(const unsigned*)s2;
  const unsigned c0=su[lane], c1=su[64+lane], c2=su[128+lane];
  __syncthreads();                     // scratch reads done before state writes

  // ---- state: |0..0> -> thread 0, slot 0 in every frame ----
  f2 S[8], Sn[8];
  #pragma unroll
  for(int k=0;k<8;++k){ S[k].x=0.f; S[k].y=0.f; }
  if(t==0) S[0].x=1.0f;

  do_pair<0>(S,Sn,c0,c1,c2,t,s2,s4);
  do_pair<1>(S,Sn,c0,c1,c2,t,s2,s4);
  do_pair<2>(S,Sn,c0,c1,c2,t,s2,s4);
  do_pair<3>(S,Sn,c0,c1,c2,t,s2,s4);
  do_pair<4>(S,Sn,c0,c1,c2,t,s2,s4);
  do_pair<5>(S,Sn,c0,c1,c2,t,s2,s4);
  do_pair<6>(S,Sn,c0,c1,c2,t,s2,s4);
  do_pair<7>(S,Sn,c0,c1,c2,t,s2,s4);   // final state in Sn

  // ---- measurement: 8-pt WHT over z + thread signs ----
  float H[8];
  #pragma unroll
  for(int z=0;z<8;++z) H[z]=fmaf(Sn[z].x,Sn[z].x, Sn[z].y*Sn[z].y);
  #pragma unroll
  for(int st=1;st<8;st<<=1){
    #pragma unroll
    for(int z=0;z<8;++z){
      if(z & st) continue;
      float a0=H[z], a1=H[z|st];
      H[z]=a0+a1; H[z|st]=a0-a1;
    }
  }
  float acc[12];
  #pragma unroll
  for(int q=0;q<12;++q){
    const unsigned ls=((unsigned)(__popc(hA.mq[q]&t)&1))<<31;
    acc[q]=__uint_as_float(__float_as_uint(H[hA.uq[q]])^ls);
  }

  __syncthreads();                     // all pair-7 reads done -> LDS reusable
  const int wv=t>>6;                   // 0..7
  #pragma unroll
  for(int q=0;q<12;++q){
    float v=acc[q];
    #pragma unroll
    for(int off=32;off>0;off>>=1) v += __shfl_down(v,off,64);
    if(lane==0) sf[wv*12+q]=v;
  }
  __syncthreads();
  if(t<12){
    float s=0.f;
    #pragma unroll
    for(int w2=0;w2<8;++w2) s += sf[w2*12+t];
    sf[96+t]=s;
  }
  __syncthreads();

  // ---- epilogue MLP on wave 0 (r3/r6-validated) ----
  if(t<64){
    float a=b3[t];
    #pragma unroll
    for(int k=0;k<12;++k) a=fmaf(sf[96+k],W3[k*64+t],a);
    float h2=tanhf(a);
    float p0=h2*W4[2*t+0], p1=h2*W4[2*t+1];
    #pragma unroll
    for(int off=32;off>0;off>>=1){ p0+=__shfl_down(p0,off,64); p1+=__shfl_down(p1,off,64); }
    if(t==0){ out[2*b+0]=p0+b4[0]; out[2*b+1]=p1+b4[1]; }
  }
}

extern "C" void kernel_launch(void* const* d_in, const int* in_sizes, int n_in,
                              void* d_out, int out_size, void* d_ws, size_t ws_size,
                              hipStream_t stream)
{
  const float* noise=(const float*)d_in[0];
  const float* W1=(const float*)d_in[1];
  const float* b1=(const float*)d_in[2];
  const float* W2=(const float*)d_in[3];
  const float* b2=(const float*)d_in[4];
  const float* W3=(const float*)d_in[5];
  const float* b3=(const float*)d_in[6];
  const float* W4=(const float*)d_in[7];
  const float* b4=(const float*)d_in[8];
  float* out=(float*)d_out;
  const int batch=in_sizes[0]/NQ;   // 4096
  qgen<<<batch,TPB,0,stream>>>(noise,W1,b1,W2,b2,W3,b3,W4,b4,out);
}

// Round 12
// 205.561 us; speedup vs baseline: 1.0606x; 1.0606x over previous
//
#include <hip/hip_runtime.h>
#include <math.h>

#define NQ  12
#define TPB 256

typedef __attribute__((ext_vector_type(2))) float f2;

// ================= compile-time GF(2) machinery (r8/r9-validated) =================
// Folded space: gate q,layer l pairs x <-> x^v, role=parity(r&x), r_j.v_i=delta_ij.
// PAIRED passes (2m,2m+1) share lane basis B[0..7]; intra-pair transition is a
// wave-internal ds_bpermute (slot relabel sz, lane-xor gx). Boundary m: layout
// elem = sigma(Tp x); writes 8 contiguous swizzled b128, next-pair reads 16
// conflict-floor b64 (residues engineered through the boundary map).

struct GF12 { unsigned row[12]; };

constexpr GF12 gf_id(){ GF12 m{}; for(int i=0;i<12;i++) m.row[i]=1u<<i; return m; }
constexpr GF12 gf_mul(const GF12&A,const GF12&B){
  GF12 r{};
  for(int i=0;i<12;i++){ unsigned acc=0;
    for(int k=0;k<12;k++) if((A.row[i]>>k)&1u) acc ^= B.row[k];
    r.row[i]=acc; }
  return r;
}
constexpr unsigned gf_apply(const GF12&A, unsigned x){
  unsigned y=0;
  for(int i=0;i<12;i++) y |= (unsigned)(__builtin_popcount(A.row[i]&x)&1)<<i;
  return y;
}
constexpr GF12 gf_cnot(int q){ GF12 m=gf_id(); int c=11-q, t=11-((q+1)%12); m.row[t]^=(1u<<c); return m; }
constexpr GF12 gf_inv(const GF12&A){
  unsigned a[12], inv[12];
  for(int i=0;i<12;i++){ a[i]=A.row[i]; inv[i]=1u<<i; }
  for(int c=0;c<12;c++){
    int p=-1;
    for(int r2=c;r2<12;r2++) if((a[r2]>>c)&1u){p=r2;break;}
    if(p<0) continue;
    unsigned ta=a[c]; a[c]=a[p]; a[p]=ta;
    unsigned ti=inv[c]; inv[c]=inv[p]; inv[p]=ti;
    for(int r2=0;r2<12;r2++) if(r2!=c && ((a[r2]>>c)&1u)){ a[r2]^=a[c]; inv[r2]^=inv[c]; }
  }
  GF12 R{}; for(int i=0;i<12;i++) R.row[i]=inv[i];
  return R;
}

struct Red { unsigned arr[12]; int hb[12]; int n; };
constexpr unsigned red_reduce(const Red& R, unsigned y){
  for(int i=0;i<R.n;i++) if((y>>R.hb[i])&1u) y ^= R.arr[i];
  return y;
}
constexpr bool red_add(Red& R, unsigned cand){
  unsigned y = red_reduce(R, cand);
  if(!y) return false;
  int h=0;
  for(int b2=11;b2>=1;b2--) if((y>>b2)&1u){ h=b2; break; }
  R.arr[R.n]=y; R.hb[R.n]=h; R.n++;
  return true;
}

struct PairT {
  unsigned M0[4], M1[4];
  unsigned sz[16], gx[16];
  unsigned rB[8], roff[16];
};
struct AllT { PairT pr[6]; unsigned mq[12], uq[12]; bool ok; };

constexpr AllT makeAll(){
  AllT T{}; T.ok=true;
  GF12 D=gf_id(); for(int q=0;q<12;q++) D=gf_mul(gf_cnot(q),D);
  GF12 Cm=gf_id(); for(int q=11;q>=0;q--) Cm=gf_mul(gf_cnot(q),Cm);
  unsigned V[12][4]{},R[12][4]{},rfin[12]{};
  GF12 Mm=gf_id(), Mi=gf_id();
  for(int l=0;l<4;l++){
    for(int q=0;q<12;q++){
      int b=11-q; unsigned v=0;
      for(int j=0;j<12;j++) v|=((Mi.row[j]>>b)&1u)<<j;
      V[l*3+q/4][q&3]=v; R[l*3+q/4][q&3]=Mm.row[b];
    }
    Mm=gf_mul(D,Mm); Mi=gf_mul(Cm,Mi);
  }
  for(int q=0;q<12;q++) rfin[q]=Mm.row[11-q];

  GF12 Sg=gf_id(); Sg.row[1]|=1u<<4; Sg.row[2]|=1u<<5; Sg.row[3]|=1u<<6;

  GF12 Tprev{}, Tprev_inv{};
  for(int m=0;m<6;m++){
    const int p0=2*m, p1=p0+1;
    for(int pp=p0;pp<=p1;pp++) for(int j=0;j<4;j++) for(int i=0;i<4;i++){
      int par=__builtin_popcount(R[pp][j]&V[pp][i])&1;
      if(par!=((i==j)?1:0)) T.ok=false;
    }
    Red S{};
    for(int i=0;i<4;i++){ red_add(S,V[p0][i]); red_add(S,V[p1][i]); }
    for(unsigned x=1;x<4096 && S.n<10;x++) red_add(S,x);
    if(S.n!=10) T.ok=false;
    Red S12=S, RA{}, RB{};
    for(int i=0;i<4;i++){ red_add(RA,V[p0][i]); red_add(RB,V[p1][i]); }
    unsigned B[8]{};
    Red resR{};
    for(int k=0;k<6;k++){
      unsigned pick=0;
      if(m>0){
        unsigned res=(k<4)?(1u<<k):0u;
        for(unsigned hi=(k<4)?0u:1u; hi<256 && !pick; hi++){
          unsigned y=res|(hi<<4);
          unsigned x=gf_apply(Tprev_inv,y);
          if(red_reduce(S,x)) continue;
          if(!red_reduce(RA,x)) continue;
          if(!red_reduce(RB,x)) continue;
          pick=x;
        }
        for(unsigned y=1;y<4096 && !pick;y++){
          unsigned x=gf_apply(Tprev_inv,y);
          if(red_reduce(S,x)) continue;
          if(!red_reduce(RA,x)) continue;
          if(!red_reduce(RB,x)) continue;
          if(k<4){ unsigned rb=y&15u; if(!rb || !red_reduce(resR,rb)) continue; }
          pick=x;
        }
      }
      if(!pick){
        for(unsigned x=1;x<4096 && !pick;x++){
          if(red_reduce(S,x)) continue;
          if(!red_reduce(RA,x)) continue;
          if(!red_reduce(RB,x)) continue;
          pick=x;
        }
      }
      if(!pick){ T.ok=false; pick=1; }
      if(m>0 && k<4){ unsigned rb=gf_apply(Tprev,pick)&15u; if(rb) red_add(resR,rb); }
      red_add(RA,pick); red_add(RB,pick);
      B[k]=pick;
    }
    for(int k=6;k<8;k++){
      unsigned pick=0;
      for(unsigned x=1;x<4096 && !pick;x++) if(red_reduce(S12,x)) pick=x;
      if(!pick){ T.ok=false; pick=1; }
      red_add(S12,pick); B[k]=pick;
    }
    if(S12.n!=12) T.ok=false;
    GF12 Z{};
    for(int i=0;i<12;i++){
      unsigned rr=0;
      for(int k=0;k<4;k++) rr |= ((V[p1][k]>>i)&1u)<<k;
      for(int k=0;k<8;k++) rr |= ((B[k]>>i)&1u)<<(4+k);
      Z.row[i]=rr;
    }
    GF12 Tp=gf_inv(Z);
    { GF12 I2=gf_mul(Tp,Z); for(int i=0;i<12;i++) if(I2.row[i]!=(1u<<i)) T.ok=false; }
    for(int j=0;j<4;j++){
      unsigned m0=0,m1=0;
      for(int k=0;k<8;k++){
        m0 |= (unsigned)(__builtin_popcount(R[p0][j]&B[k])&1)<<k;
        m1 |= (unsigned)(__builtin_popcount(R[p1][j]&B[k])&1)<<k;
      }
      T.pr[m].M0[j]=m0; T.pr[m].M1[j]=m1;
    }
    unsigned zeta[4]{}, gam[4]{};
    for(int i=0;i<4;i++){
      unsigned d=gf_apply(Tp,V[p0][i]);
      if(d>>10) T.ok=false;
      zeta[i]=d&15u; gam[i]=(d>>4)&63u;
    }
    unsigned zmap[16]{}; bool seen[16]{};
    for(int z=0;z<16;z++){
      unsigned zz=0;
      for(int i=0;i<4;i++) if((z>>i)&1) zz^=zeta[i];
      zmap[z]=zz;
      if(seen[zz]) T.ok=false; seen[zz]=true;
    }
    for(int zp=0;zp<16;zp++){
      unsigned src=0;
      for(int z=0;z<16;z++) if(zmap[z]==(unsigned)zp) src=(unsigned)z;
      unsigned gg=0;
      for(int i=0;i<4;i++) if((src>>i)&1) gg^=gam[i];
      T.pr[m].sz[zp]=src; T.pr[m].gx[zp]=gg;
    }
    for(int z=0;z<16;z++){
      unsigned c0=0,c1=0,gg=0,bb=0;
      for(int i=0;i<4;i++){
        if((z>>i)&1){ c0^=V[p0][i]; gg^=gam[i]; }
        if((zmap[z]>>i)&1) c1^=V[p1][i];
      }
      for(int k=0;k<6;k++) if((gg>>k)&1) bb^=B[k];
      if((c0^c1^bb)!=0) T.ok=false;
    }
    if(m>0){
      for(int k=0;k<8;k++) T.pr[m].rB[k]=gf_apply(Tprev,B[k]);
      for(int z=0;z<16;z++){
        unsigned c=0;
        for(int i=0;i<4;i++) if((z>>i)&1) c^=V[p0][i];
        T.pr[m].roff[z]=gf_apply(Tprev,c);
      }
    }
    GF12 Tnew=gf_mul(Sg,Tp), Tnew_inv=gf_mul(Z,Sg);
    { GF12 I2=gf_mul(Tnew,Tnew_inv); for(int i=0;i<12;i++) if(I2.row[i]!=(1u<<i)) T.ok=false; }
    Tprev=Tnew; Tprev_inv=Tnew_inv;
    if(m==5){
      for(int q=0;q<12;q++){
        unsigned u=0,mm=0;
        for(int i=0;i<4;i++) u |= (unsigned)(__builtin_popcount(rfin[q]&V[11][i])&1)<<i;
        for(int k=0;k<8;k++) mm |= (unsigned)(__builtin_popcount(rfin[q]&B[k])&1)<<k;
        T.uq[q]=u; T.mq[q]=mm;
      }
    }
  }
  return T;
}

constexpr AllT hA = makeAll();
static_assert(hA.ok, "GF(2) paired-bpermute table self-check failed");

// ---- FORCED packed butterfly: explicit VOP3P asm, 8 ops/pair, zero movs ----
// G1=(ar, ai'), G2=(br', bi)  (ai',br' carry role sign — r1-validated trick).
// X' = (ar*xr - ai*xi + br*yr - bi*yi,  ar*xi + ai*xr + br*yi + bi*yr)
// Y' = (ar*yr + ai*yi - br*xr - bi*xi,  ar*yi - ai*yr + bi*xr - br*xi)
// op_sel broadcasts halves / swaps (xi,xr); neg_lo/neg_hi fold all signs.
__device__ __forceinline__ f2 pk_mul_hib_swap(f2 g, f2 y){   // (-g.hi*y.hi, g.hi*y.lo)
  f2 d;
  asm("v_pk_mul_f32 %0, %1, %2 op_sel:[1,1] op_sel_hi:[1,0] neg_lo:[1,0]"
      : "=v"(d) : "v"(g), "v"(y));
  return d;
}
__device__ __forceinline__ void pk_fma_lob(f2& a, f2 g, f2 x){       // a += g.lo * x
  asm("v_pk_fma_f32 %0, %1, %2, %0 op_sel:[0,0,0] op_sel_hi:[0,1,1]"
      : "+v"(a) : "v"(g), "v"(x));
}
__device__ __forceinline__ void pk_fma_lob_negall(f2& a, f2 g, f2 x){ // a += -g.lo * x
  asm("v_pk_fma_f32 %0, %1, %2, %0 op_sel:[0,0,0] op_sel_hi:[0,1,1] neg_lo:[1,0,0] neg_hi:[1,0,0]"
      : "+v"(a) : "v"(g), "v"(x));
}
__device__ __forceinline__ void pk_fma_hib_swap_neglo(f2& a, f2 g, f2 x){ // a += (-g.hi,g.hi)*(x.hi,x.lo)
  asm("v_pk_fma_f32 %0, %1, %2, %0 op_sel:[1,1,0] op_sel_hi:[1,0,1] neg_lo:[1,0,0]"
      : "+v"(a) : "v"(g), "v"(x));
}
__device__ __forceinline__ void pk_fma_hib_swap_neghi(f2& a, f2 g, f2 x){ // a += (g.hi,-g.hi)*(x.hi,x.lo)
  asm("v_pk_fma_f32 %0, %1, %2, %0 op_sel:[1,1,0] op_sel_hi:[1,0,1] neg_hi:[1,0,0]"
      : "+v"(a) : "v"(g), "v"(x));
}

#define GATE_PK(SS,MM,JJ) do { \
    const int _lb = pl + 4*(JJ); \
    const unsigned _sg = ((unsigned)(__popc((MM) & (unsigned)t) & 1)) << 31; \
    f2 G1, G2; \
    G1.x = __uint_as_float((unsigned)__builtin_amdgcn_readlane((int)cur, _lb+0)); \
    G1.y = __uint_as_float(((unsigned)__builtin_amdgcn_readlane((int)cur, _lb+1)) ^ _sg); \
    G2.x = __uint_as_float(((unsigned)__builtin_amdgcn_readlane((int)cur, _lb+2)) ^ _sg); \
    G2.y = __uint_as_float((unsigned)__builtin_amdgcn_readlane((int)cur, _lb+3)); \
    _Pragma("unroll") \
    for (int s0=0; s0<16; ++s0){ \
      if ((s0 >> (JJ)) & 1) continue; \
      const int s1 = s0 | (1<<(JJ)); \
      const f2 X = SS[s0], Y = SS[s1]; \
      f2 u = pk_mul_hib_swap(G2, Y); \
      pk_fma_lob(u, G2, Y); \
      pk_fma_hib_swap_neglo(u, G1, X); \
      pk_fma_lob(u, G1, X); \
      f2 v = pk_mul_hib_swap(G2, X); \
      pk_fma_lob_negall(v, G2, X); \
      pk_fma_hib_swap_neghi(v, G1, Y); \
      pk_fma_lob(v, G1, Y); \
      SS[s0] = u; SS[s1] = v; \
    } \
  } while(0)

template<int M>
__device__ __forceinline__ void do_pair(f2 S[16], f2 Sn[16],
                                        unsigned c0, unsigned c1, unsigned c2,
                                        unsigned t, float2* s2, float4* s4)
{
  constexpr PairT P = hA.pr[M];
  if constexpr (M > 0){
    unsigned base=0;
    #pragma unroll
    for(int k=0;k<8;++k) base ^= ((t>>k)&1u) ? P.rB[k] : 0u;
    #pragma unroll
    for(int z=0;z<16;++z){ float2 v=s2[base ^ P.roff[z]]; S[z].x=v.x; S[z].y=v.y; }
  }
  // pass p0 = 2M
  { constexpr int ci=(2*M)>>2;
    const unsigned cur=(ci==0)?c0:((ci==1)?c1:c2);
    const int pl=((2*M)&3)<<4;
    GATE_PK(S,P.M0[0],0); GATE_PK(S,P.M0[1],1); GATE_PK(S,P.M0[2],2); GATE_PK(S,P.M0[3],3); }
  // wave-internal transition (r8-validated)
  { const unsigned t4=t<<2;
    #pragma unroll
    for(int zp=0; zp<16; ++zp){
      const int idx=(int)(t4 ^ (P.gx[zp]<<2));
      Sn[zp].x=__uint_as_float((unsigned)__builtin_amdgcn_ds_bpermute(idx,(int)__float_as_uint(S[P.sz[zp]].x)));
      Sn[zp].y=__uint_as_float((unsigned)__builtin_amdgcn_ds_bpermute(idx,(int)__float_as_uint(S[P.sz[zp]].y)));
    } }
  // pass p1 = 2M+1
  { constexpr int ci=(2*M+1)>>2;
    const unsigned cur=(ci==0)?c0:((ci==1)?c1:c2);
    const int pl=((2*M+1)&3)<<4;
    GATE_PK(Sn,P.M1[0],0); GATE_PK(Sn,P.M1[1],1); GATE_PK(Sn,P.M1[2],2); GATE_PK(Sn,P.M1[3],3); }
  if constexpr (M < 5){
    __syncthreads();
    const unsigned wb=t<<3;
    #pragma unroll
    for(int k=0;k<8;++k)
      s4[wb | ((unsigned)k ^ (t&7u))] =
        make_float4(Sn[2*k].x, Sn[2*k].y, Sn[2*k+1].x, Sn[2*k+1].y);
    __syncthreads();
  }
}

__global__ void __launch_bounds__(TPB, 5)
qgen(const float* __restrict__ noise,
     const float* __restrict__ W1, const float* __restrict__ b1,
     const float* __restrict__ W2, const float* __restrict__ b2,
     const float* __restrict__ W3, const float* __restrict__ b3,
     const float* __restrict__ W4, const float* __restrict__ b4,
     float* __restrict__ out)
{
  __shared__ float2 s2[4096];          // 32 KiB -> 5 blocks/CU
  float*  sf=(float*)s2;
  float4* s4=(float4*)s2;

  const unsigned t = threadIdx.x;
  const int b = blockIdx.x;
  const int lane = t & 63;

  // ---- prologue MLP (r3/r6-validated; scratch aliased into state) ----
  if (t < 12) sf[400+t] = noise[b*12+t];
  __syncthreads();
  if (t < 64){
    float a = b1[t];
    #pragma unroll
    for (int k=0;k<12;++k) a = fmaf(sf[400+k], W1[k*64+t], a);
    sf[192+t] = tanhf(a);
  }
  __syncthreads();
  if (t < 144){
    float a = b2[t];
    #pragma unroll 16
    for (int j=0;j<64;++j) a = fmaf(sf[192+j], W2[j*144+t], a);
    sf[256+t] = a;
  }
  __syncthreads();
  if (t < 48){
    float aa = sf[256+3*t+0]*0.5f, bb = sf[256+3*t+1]*0.5f, c = sf[256+3*t+2]*0.5f;
    float sa,ca,sb,cb,sc2,cc;
    __sincosf(aa,&sa,&ca); __sincosf(bb,&sb,&cb); __sincosf(c,&sc2,&cc);
    float A=cb*ca, B=sb*sa, Cc=sb*ca, Dd=cb*sa;
    s4[t] = make_float4(fmaf(cc,A,  sc2*B),  fmaf(cc,B, -sc2*A),
                        fmaf(-cc,Cc,-sc2*Dd), fmaf(sc2,Cc,-cc*Dd));
  }
  __syncthreads();
  const unsigned* su=(const unsigned*)s2;
  const unsigned c0=su[lane], c1=su[64+lane], c2=su[128+lane];
  __syncthreads();                     // scratch reads done before state writes

  // ---- state: |0..0> -> lane 0, slot 0 in every frame ----
  f2 S[16], Sn[16];
  #pragma unroll
  for(int k=0;k<16;++k){ S[k].x=0.f; S[k].y=0.f; }
  if(t==0) S[0].x=1.0f;

  do_pair<0>(S,Sn,c0,c1,c2,t,s2,s4);
  do_pair<1>(S,Sn,c0,c1,c2,t,s2,s4);
  do_pair<2>(S,Sn,c0,c1,c2,t,s2,s4);
  do_pair<3>(S,Sn,c0,c1,c2,t,s2,s4);
  do_pair<4>(S,Sn,c0,c1,c2,t,s2,s4);
  do_pair<5>(S,Sn,c0,c1,c2,t,s2,s4);   // final state in Sn

  // ---- measurement: 16-pt WHT over z (r6-validated) ----
  float H[16];
  #pragma unroll
  for(int z=0;z<16;++z) H[z]=fmaf(Sn[z].x,Sn[z].x, Sn[z].y*Sn[z].y);
  #pragma unroll
  for(int st=1;st<16;st<<=1){
    #pragma unroll
    for(int z=0;z<16;++z){
      if(z & st) continue;
      float a0=H[z], a1=H[z|st];
      H[z]=a0+a1; H[z|st]=a0-a1;
    }
  }
  float acc[12];
  #pragma unroll
  for(int q=0;q<12;++q){
    const unsigned ls=((unsigned)(__popc(hA.mq[q]&t)&1))<<31;
    acc[q]=__uint_as_float(__float_as_uint(H[hA.uq[q]])^ls);
  }

  __syncthreads();                     // all pair-5 reads done -> LDS reusable
  const int wv=t>>6;
  #pragma unroll
  for(int q=0;q<12;++q){
    float v=acc[q];
    #pragma unroll
    for(int off=32;off>0;off>>=1) v += __shfl_down(v,off,64);
    if(lane==0) sf[wv*12+q]=v;
  }
  __syncthreads();
  if(t<12) sf[64+t]=sf[t]+sf[12+t]+sf[24+t]+sf[36+t];
  __syncthreads();

  // ---- epilogue MLP on wave 0 (r3/r6-validated) ----
  if(t<64){
    float a=b3[t];
    #pragma unroll
    for(int k=0;k<12;++k) a=fmaf(sf[64+k],W3[k*64+t],a);
    float h2=tanhf(a);
    float p0=h2*W4[2*t+0], p1=h2*W4[2*t+1];
    #pragma unroll
    for(int off=32;off>0;off>>=1){ p0+=__shfl_down(p0,off,64); p1+=__shfl_down(p1,off,64); }
    if(t==0){ out[2*b+0]=p0+b4[0]; out[2*b+1]=p1+b4[1]; }
  }
}

extern "C" void kernel_launch(void* const* d_in, const int* in_sizes, int n_in,
                              void* d_out, int out_size, void* d_ws, size_t ws_size,
                              hipStream_t stream)
{
  const float* noise=(const float*)d_in[0];
  const float* W1=(const float*)d_in[1];
  const float* b1=(const float*)d_in[2];
  const float* W2=(const float*)d_in[3];
  const float* b2=(const float*)d_in[4];
  const float* W3=(const float*)d_in[5];
  const float* b3=(const float*)d_in[6];
  const float* W4=(const float*)d_in[7];
  const float* b4=(const float*)d_in[8];
  float* out=(float*)d_out;
  const int batch=in_sizes[0]/NQ;   // 4096
  qgen<<<batch,TPB,0,stream>>>(noise,W1,b1,W2,b2,W3,b3,W4,b4,out);
}